// Round 2
// 715.627 us; speedup vs baseline: 1.0342x; 1.0342x over previous
//
#include <hip/hip_runtime.h>

#define DD 51
#define DM 50
#define PD 52          // padded LDS row stride (16B-aligned rows: 52*4 = 208 B)
#define BB 8192
#define MM (DD*DD)     // 2601
#define NBUCKET 1024

__device__ __forceinline__ float wave_sum(float v) {
    #pragma unroll
    for (int off = 32; off; off >>= 1) v += __shfl_xor(v, off);
    return v;
}

// p / 51 for p in [0, 2601], magic = ceil(2^32/51)
__device__ __forceinline__ int div51(int p) {
    return (int)((((unsigned long long)(unsigned)p) * 84215046ull) >> 32);
}

// ---------------- zero the accumulator buckets ----------------
__global__ __launch_bounds__(256) void zero_kernel(float* __restrict__ buckets) {
    buckets[blockIdx.x * 256 + threadIdx.x] = 0.f;
}

// ---------------- task kernel A: matvec losses (types 0-3) + misc (type 4) --
// ONE wave per task. Matrix staged at row stride 52 so the per-lane row dot is
// 13 ds_read_b128 + 13 broadcast b128 (vs ~102 ds_read_b32 unpadded).
// Algebraic fusion: dr - cr = M @ (d - c): ONE matvec for all four types; nf1
// additionally needs M[50,:].c and M[50,:].d (two wave reductions).
// Single-wave __syncthreads() (trivial s_barrier) fences LDS producer->consumer.
// LDS 10.8 KB -> 14 blocks/CU.
__global__ __launch_bounds__(64, 2) void taskA_kernel(
    const int* __restrict__ nf1, const int* __restrict__ nf3,
    const int* __restrict__ nf4, const int* __restrict__ nfneg,
    const int* __restrict__ nf2, const int* __restrict__ top,
    const int* __restrict__ radius,
    const float* __restrict__ cls,
    const float* __restrict__ rel,
    float* __restrict__ buckets)
{
    alignas(16) __shared__ float Mw[DD * PD];   // [51][52], col 51 zeroed
    alignas(16) __shared__ float vb[PD];        // v = d - c, padded with 0
    const int task = blockIdx.x;
    const int type = task >> 13;
    const int b    = task & (BB - 1);
    const int lane = threadIdx.x;

    if (type < 4) {
        int ci, ri, di;
        if (type == 0)      { ci = nf1[3*b];   ri = nf1[3*b+1];   di = nf1[3*b+2]; }
        else if (type == 1) { ci = nf3[3*b];   ri = nf3[3*b+1];   di = nf3[3*b+2]; }
        else if (type == 2) { ri = nf4[3*b];   ci = nf4[3*b+1];   di = nf4[3*b+2]; }
        else                { ci = nfneg[3*b]; ri = nfneg[3*b+1]; di = nfneg[3*b+2]; }

        float cv = 0.f, dv = 0.f;
        if (lane < DD) {
            cv = cls[(size_t)ci * DD + lane];
            dv = cls[(size_t)di * DD + lane];
        }
        if (lane < PD) vb[lane] = (lane < DD) ? (dv - cv) : 0.f;
        if (lane < DD) Mw[lane * PD + (PD - 1)] = 0.f;   // zero pad column

        // stage M: coalesced global dwords -> padded LDS rows (addr = p + p/51)
        const float* Mg = rel + (size_t)ri * MM;
        #pragma unroll
        for (int k = 0; k < 40; ++k) {
            int p = lane + (k << 6);
            Mw[p + div51(p)] = Mg[p];
        }
        { int p = lane + 2560; if (p < MM) Mw[p + div51(p)] = Mg[p]; }
        __syncthreads();   // single-wave barrier: fence LDS write->read

        // u[lane] = (M @ v)[lane] : 13 aligned b128 row reads + 13 b128 broadcasts
        float acc = 0.f;
        if (lane < DD) {
            const float4* rp = (const float4*)(Mw + lane * PD);
            const float4* vp = (const float4*)vb;
            #pragma unroll
            for (int q = 0; q < 13; ++q) {
                float4 a = rp[q], w = vp[q];
                acc = fmaf(a.x, w.x, acc);
                acc = fmaf(a.y, w.y, acc);
                acc = fmaf(a.z, w.z, acc);
                acc = fmaf(a.w, w.w, acc);
            }
        }
        float mk = (lane < DM) ? 1.f : 0.f;     // first 50 components only
        float e2 = wave_sum(acc * acc * mk);
        float c2 = wave_sum(cv * cv * mk);
        float d2 = wave_sum(dv * dv * mk);
        float c50 = __shfl(cv, DM);
        float d50 = __shfl(dv, DM);
        float s1 = 0.f, s2 = 0.f;
        if (type == 0) {                        // nf1 needs cr[50], dr[50]
            float m50 = (lane < DD) ? Mw[DM * PD + lane] : 0.f;
            s1 = wave_sum(m50 * cv);
            s2 = wave_sum(m50 * dv);
        }
        if (lane == 0) {
            float euc = sqrtf(e2);
            float reg = fabsf(sqrtf(c2) - 1.f) + fabsf(sqrtf(d2) - 1.f);
            float L;
            if (type == 0) {
                float rc = fmaxf(s1, 0.f), rd = fmaxf(s2, 0.f);
                L = fmaxf(euc + rc - rd, 0.f) + reg;            // nf1
            } else if (type == 1) {
                float rc = fmaxf(c50, 0.f), rd = fmaxf(d50, 0.f);
                L = fmaxf(euc + rc - rd, 0.f) + reg;            // nf3
            } else if (type == 2) {
                float rc = fmaxf(c50, 0.f), rd = fmaxf(d50, 0.f);
                L = fmaxf(euc - (rc + rd), 0.f) + reg;          // nf4
            } else {
                float rc = fmaxf(c50, 0.f), rd = fmaxf(d50, 0.f);
                L = -(euc - rc - rd) + reg;                     // nf3_neg
            }
            atomicAdd(&buckets[task & (NBUCKET - 1)], L);
        }
    } else {
        // ---------------- misc: nf2 + top + radius ----------------
        int i0 = nf2[3*b], i1 = nf2[3*b+1], i2 = nf2[3*b+2];
        float cv = 0.f, dv = 0.f, ev = 0.f;
        if (lane < DD) {
            cv = cls[(size_t)i0 * DD + lane];
            dv = cls[(size_t)i1 * DD + lane];
            ev = cls[(size_t)i2 * DD + lane];
        }
        float t50 = cls[(size_t)top[b]    * DD + DM];   // uniform -> scalar load
        float r50 = cls[(size_t)radius[b] * DD + DM];
        float m = (lane < DM) ? 1.f : 0.f;
        float s_dc = wave_sum((dv - cv) * (dv - cv) * m);
        float s_ec = wave_sum((ev - cv) * (ev - cv) * m);
        float s_ed = wave_sum((ev - dv) * (ev - dv) * m);
        float s_c  = wave_sum(cv * cv * m);
        float s_d  = wave_sum(dv * dv * m);
        float s_e  = wave_sum(ev * ev * m);
        float c50 = __shfl(cv, DM), d50 = __shfl(dv, DM), e50 = __shfl(ev, DM);
        if (lane == 0) {
            float rc = fmaxf(c50, 0.f), rd = fmaxf(d50, 0.f), re = fmaxf(e50, 0.f);
            float L = fmaxf(sqrtf(s_dc) - (rc + rd), 0.f)
                    + fmaxf(sqrtf(s_ec) - rc, 0.f)
                    + fmaxf(sqrtf(s_ed) - rd, 0.f)
                    + fmaxf(fminf(rc, rd) - re, 0.f)
                    + fabsf(sqrtf(s_c) - 1.f)
                    + fabsf(sqrtf(s_d) - 1.f)
                    + fabsf(sqrtf(s_e) - 1.f)
                    + fabsf(fmaxf(t50, 0.f) - 5.f)
                    - fminf(r50, 0.f);
            atomicAdd(&buckets[task & (NBUCKET - 1)], L);
        }
    }
}

// ---------------- chain loss: mean |E - C@D|, ONE wave per block ----------
// 49 lanes each own an 8x8 output tile: per k only 4 ds_read_b128 feed 64 FMA
// (1 B LDS / FMA). After the k-loop, acc tiles are written back into the CsT
// region and |E - acc| is accumulated with a fully-coalesced sweep (instead of
// 64 scattered E gathers per thread). LDS 21.2 KB -> 7 waves/CU, VALU-bound.
__global__ __launch_bounds__(64, 2) void chainB_kernel(
    const int* __restrict__ nfc,
    const float* __restrict__ rel,
    float* __restrict__ buckets)
{
    alignas(16) __shared__ float lds[2 * DD * PD + 8];  // +8: benign b128 overshoot of last row
    float* CsT = lds;            // CsT[k*52 + i] = C[i][k]
    float* Dsm = lds + DD * PD;  // Dsm[k*52 + j] = D[k][j]
    const int b    = blockIdx.x;
    const int lane = threadIdx.x;
    int ic = nfc[3*b], id = nfc[3*b+1], ie = nfc[3*b+2];
    const float* Cg = rel + (size_t)ic * MM;
    const float* Dg = rel + (size_t)id * MM;
    const float* Eg = rel + (size_t)ie * MM;

    #pragma unroll 10
    for (int t = 0; t < 40; ++t) {
        int p = lane + (t << 6);
        int r = div51(p), c = p - r * DD;
        CsT[c * PD + r] = Cg[p];      // transposed store (bank conflicts accepted)
        Dsm[p + r]      = Dg[p];      // linear store, conflict-free
    }
    { int p = lane + 2560;
      if (p < MM) { int r = div51(p), c = p - r * DD; CsT[c*PD + r] = Cg[p]; Dsm[p + r] = Dg[p]; } }
    __syncthreads();   // single-wave barrier: fence staging -> k-loop

    int ti = 0, tj = 0;
    if (lane < 49) { ti = lane / 7; tj = lane - ti * 7; }
    const int i0 = ti * 8, j0 = tj * 8;
    float a2[8][8];
    #pragma unroll
    for (int r = 0; r < 8; ++r)
        #pragma unroll
        for (int c = 0; c < 8; ++c) a2[r][c] = 0.f;

    if (lane < 49) {
        #pragma unroll 3
        for (int k = 0; k < DD; ++k) {
            const float4* cp = (const float4*)(CsT + k * PD + i0);
            const float4* dp = (const float4*)(Dsm + k * PD + j0);
            float4 ca0 = cp[0], ca1 = cp[1];
            float4 db0 = dp[0], db1 = dp[1];
            float A_[8] = {ca0.x, ca0.y, ca0.z, ca0.w, ca1.x, ca1.y, ca1.z, ca1.w};
            float B_[8] = {db0.x, db0.y, db0.z, db0.w, db1.x, db1.y, db1.z, db1.w};
            #pragma unroll
            for (int r = 0; r < 8; ++r)
                #pragma unroll
                for (int c = 0; c < 8; ++c)
                    a2[r][c] = fmaf(A_[r], B_[c], a2[r][c]);
        }
    }
    __syncthreads();   // k-loop reads done before acc overwrites CsT region

    if (lane < 49) {
        // write acc tiles into the (now dead) CsT region: Acc[i*52 + j]
        #pragma unroll
        for (int r = 0; r < 8; ++r) {
            int i = i0 + r;
            if (i < DD) {
                *(float4*)(lds + i * PD + j0) =
                    make_float4(a2[r][0], a2[r][1], a2[r][2], a2[r][3]);
                if (tj < 6)
                    *(float4*)(lds + i * PD + j0 + 4) =
                        make_float4(a2[r][4], a2[r][5], a2[r][6], a2[r][7]);
            }
        }
    }
    __syncthreads();   // acc visible before coalesced sweep

    // coalesced |E - acc| sweep (element (r,c) lives at p + p/51 = r*52 + c)
    float local = 0.f;
    #pragma unroll 10
    for (int t = 0; t < 40; ++t) {
        int p = lane + (t << 6);
        local += fabsf(Eg[p] - lds[p + div51(p)]);
    }
    { int p = lane + 2560; if (p < MM) local += fabsf(Eg[p] - lds[p + div51(p)]); }
    local = wave_sum(local);
    if (lane == 0)
        atomicAdd(&buckets[b & (NBUCKET - 1)], local * (1.f / (float)MM));
}

// ---------------- finalize: mean over B ----------------
__global__ __launch_bounds__(256) void finalize_kernel(
    const float* __restrict__ buckets, float* __restrict__ out)
{
    int t = threadIdx.x;
    float v = buckets[t] + buckets[t + 256] + buckets[t + 512] + buckets[t + 768];
    v = wave_sum(v);
    __shared__ float ws[4];
    if ((t & 63) == 0) ws[t >> 6] = v;
    __syncthreads();
    if (t == 0) out[0] = (ws[0] + ws[1] + ws[2] + ws[3]) * (1.f / (float)BB);
}

extern "C" void kernel_launch(void* const* d_in, const int* in_sizes, int n_in,
                              void* d_out, int out_size, void* d_ws, size_t ws_size,
                              hipStream_t stream) {
    const int* nf1     = (const int*)d_in[0];
    const int* nf2     = (const int*)d_in[1];
    const int* nf3     = (const int*)d_in[2];
    const int* nf4     = (const int*)d_in[3];
    const int* top     = (const int*)d_in[4];
    const int* nf3n    = (const int*)d_in[5];
    // d_in[6] = nf_inclusion (unused by reference)
    const int* nfc     = (const int*)d_in[7];
    const int* radius  = (const int*)d_in[8];
    const float* cls   = (const float*)d_in[9];
    const float* rel   = (const float*)d_in[10];

    float* buckets = (float*)d_ws;

    zero_kernel<<<NBUCKET / 256, 256, 0, stream>>>(buckets);
    taskA_kernel<<<5 * BB, 64, 0, stream>>>(nf1, nf3, nf4, nf3n, nf2, top, radius,
                                            cls, rel, buckets);
    chainB_kernel<<<BB, 64, 0, stream>>>(nfc, rel, buckets);
    finalize_kernel<<<1, 256, 0, stream>>>(buckets, (float*)d_out);
}